// Round 1
// baseline (667.563 us; speedup 1.0000x reference)
//
#include <hip/hip_runtime.h>
#include <math.h>

#define B_    16
#define TMAX  4096
#define DM    1024
#define H_    16
#define DH    64
#define SPLIT 4
#define SCALE 0.125f

// ws layout (float offsets)
#define WS_COS   0                    // TMAX*32 = 131072
#define WS_SIN   131072               // 131072
#define WS_Q     262144               // B*H*64 = 16384
#define WS_K     278528               // 16384
#define WS_V     294912               // 16384
#define WS_PO    311296               // B*H*SPLIT*64 = 65536
#define WS_PM    376832               // B*H*SPLIT = 1024
#define WS_PL    377856               // 1024
#define WS_OF    378880               // B*H*64 = 16384
// total 395264 floats = 1.58 MB

__global__ void k_table(float* __restrict__ ws) {
    int idx = blockIdx.x * 256 + threadIdx.x;   // TMAX*32 threads
    int t = idx >> 5, j = idx & 31;
    float inv = expf(-(float)j * (logf(10000.0f) / 32.0f));
    float ang = (float)t * inv;
    float s, c;
    sincosf(ang, &s, &c);
    ws[WS_COS + idx] = c;
    ws[WS_SIN + idx] = s;
}

// grid (4 echunks, 16 heads, 3 matrices), block 256 = 64 d x 4 e-subgroups
__global__ void k_qkv(const float* __restrict__ x, const float* __restrict__ Wq,
                      const float* __restrict__ Wk, const float* __restrict__ Wv,
                      float* __restrict__ ws) {
    int ec = blockIdx.x, h = blockIdx.y, mat = blockIdx.z;
    const float* W = (mat == 0) ? Wq : ((mat == 1) ? Wk : Wv);
    float* dst = ws + WS_Q + mat * (B_ * H_ * DH);
    int d = threadIdx.x & 63, grp = threadIdx.x >> 6;
    __shared__ float xs[B_][256];
    for (int i = threadIdx.x; i < B_ * 256; i += 256) {
        int b = i >> 8, e = i & 255;
        xs[b][e] = x[b * DM + ec * 256 + e];
    }
    __syncthreads();
    float acc[B_];
#pragma unroll
    for (int b = 0; b < B_; b++) acc[b] = 0.f;
    int e0 = grp * 64;
    for (int i = 0; i < 64; i++) {
        int e = e0 + i;
        float w = W[(size_t)((ec * 256 + e) * H_ + h) * DH + d];
#pragma unroll
        for (int b = 0; b < B_; b++) acc[b] += xs[b][e] * w;
    }
#pragma unroll
    for (int b = 0; b < B_; b++)
        atomicAdd(dst + (b * H_ + h) * DH + d, acc[b]);
}

// 256 blocks (b*h) x 64 threads: add bias, write k/v into cache slot P
__global__ void k_scatter(float* __restrict__ cached_key, float* __restrict__ cached_value,
                          const float* __restrict__ bq, const float* __restrict__ bk,
                          const float* __restrict__ bv, const int* __restrict__ cidx,
                          float* __restrict__ ws) {
    int bh = blockIdx.x;
    int d = threadIdx.x;
    int b = bh >> 4, h = bh & 15;
    int P = *cidx;
    float qv = ws[WS_Q + bh * 64 + d] + bq[h * 64 + d];
    ws[WS_Q + bh * 64 + d] = qv;
    size_t off = (((size_t)b * TMAX + P) * H_ + h) * DH + d;
    cached_key[off]   = ws[WS_K + bh * 64 + d] + bk[h * 64 + d];
    cached_value[off] = ws[WS_V + bh * 64 + d] + bv[h * 64 + d];
}

// grid (SPLIT, H, B), block 256
__global__ __launch_bounds__(256) void k_attn(const float* __restrict__ K,
                                              const float* __restrict__ V,
                                              const int* __restrict__ cidx,
                                              float* __restrict__ ws) {
    int s = blockIdx.x, h = blockIdx.y, b = blockIdx.z;
    int tid = threadIdx.x;
    int P = *cidx;
    int n = P + 1;
    int chunk = (n + SPLIT - 1) / SPLIT;
    int t0 = s * chunk;
    int t1 = t0 + chunk; if (t1 > n) t1 = n;
    int len = t1 - t0; if (len < 0) len = 0;
    int bh = b * H_ + h;
    const float* costab = ws + WS_COS;
    const float* sintab = ws + WS_SIN;

    __shared__ float qr[64];
    __shared__ float sc[1024];
    __shared__ float red[256];

    if (tid < 64) {
        int d = tid;
        float v;
        if (d < 32) {
            float c = costab[P * 32 + d], sn = sintab[P * 32 + d];
            v = ws[WS_Q + bh * 64 + d] * c - ws[WS_Q + bh * 64 + d + 32] * sn;
        } else {
            float c = costab[P * 32 + d - 32], sn = sintab[P * 32 + d - 32];
            v = ws[WS_Q + bh * 64 + d - 32] * sn + ws[WS_Q + bh * 64 + d] * c;
        }
        qr[d] = v;
    }
    __syncthreads();

    // Phase A: scores (one thread per position)
    float tmax = -3.0e38f;
    for (int idx = tid; idx < len; idx += 256) {
        int t = t0 + idx;
        const float4* kp = (const float4*)(K + (((size_t)b * TMAX + t) * H_ + h) * DH);
        const float4* cp = (const float4*)(costab + t * 32);
        const float4* sp = (const float4*)(sintab + t * 32);
        float acc = 0.f;
#pragma unroll
        for (int j4 = 0; j4 < 8; ++j4) {
            float4 c4 = cp[j4], s4 = sp[j4];
            float4 k1 = kp[j4], k2 = kp[j4 + 8];
            int j = j4 * 4;
            acc += k1.x * (qr[j + 0] * c4.x + qr[j + 32] * s4.x) + k2.x * (qr[j + 32] * c4.x - qr[j + 0] * s4.x);
            acc += k1.y * (qr[j + 1] * c4.y + qr[j + 33] * s4.y) + k2.y * (qr[j + 33] * c4.y - qr[j + 1] * s4.y);
            acc += k1.z * (qr[j + 2] * c4.z + qr[j + 34] * s4.z) + k2.z * (qr[j + 34] * c4.z - qr[j + 2] * s4.z);
            acc += k1.w * (qr[j + 3] * c4.w + qr[j + 35] * s4.w) + k2.w * (qr[j + 35] * c4.w - qr[j + 3] * s4.w);
        }
        float sv = acc * SCALE;
        sc[idx] = sv;
        tmax = fmaxf(tmax, sv);
    }
    red[tid] = tmax;
    __syncthreads();
    for (int st = 128; st > 0; st >>= 1) {
        if (tid < st) red[tid] = fmaxf(red[tid], red[tid + st]);
        __syncthreads();
    }
    float m = red[0];
    __syncthreads();

    float tsum = 0.f;
    for (int idx = tid; idx < len; idx += 256) {
        float p = __expf(sc[idx] - m);
        sc[idx] = p;
        tsum += p;
    }
    red[tid] = tsum;
    __syncthreads();
    for (int st = 128; st > 0; st >>= 1) {
        if (tid < st) red[tid] += red[tid + st];
        __syncthreads();
    }
    float l = red[0];
    __syncthreads();

    // Phase B: V accumulation (lane = d, coalesced)
    int d = tid & 63, grp = tid >> 6;
    float acc = 0.f;
#pragma unroll 4
    for (int idx = grp; idx < len; idx += 4) {
        acc += sc[idx] * V[(((size_t)b * TMAX + (t0 + idx)) * H_ + h) * DH + d];
    }
    red[tid] = acc;
    __syncthreads();
    if (tid < 64) {
        float o = red[tid] + red[64 + tid] + red[128 + tid] + red[192 + tid];
        ws[WS_PO + (bh * SPLIT + s) * 64 + tid] = o;
    }
    if (tid == 0) {
        ws[WS_PM + bh * SPLIT + s] = (len > 0) ? m : -1.0e30f;
        ws[WS_PL + bh * SPLIT + s] = l;
    }
}

// 256 blocks x 64 threads
__global__ void k_combine(float* __restrict__ ws) {
    int bh = blockIdx.x;
    int d = threadIdx.x;
    const float* pm = ws + WS_PM + bh * SPLIT;
    const float* pl = ws + WS_PL + bh * SPLIT;
    const float* po = ws + WS_PO + bh * SPLIT * 64;
    float m = -3.0e38f;
#pragma unroll
    for (int s = 0; s < SPLIT; s++) m = fmaxf(m, pm[s]);
    float l = 0.f, o = 0.f;
#pragma unroll
    for (int s = 0; s < SPLIT; s++) {
        float w = __expf(pm[s] - m);
        l += pl[s] * w;
        o += po[s * 64 + d] * w;
    }
    ws[WS_OF + bh * 64 + d] = o / l;
}

// grid (16 echunks, 4 hdchunks), block 256 = 64 e x 4 hd-subgroups
__global__ void k_oproj(const float* __restrict__ Wo, const float* __restrict__ bo,
                        const float* __restrict__ ws, float* __restrict__ out) {
    int ec = blockIdx.x, hc = blockIdx.y;
    int e_local = threadIdx.x & 63, grp = threadIdx.x >> 6;
    int e = ec * 64 + e_local;
    const float* of = ws + WS_OF;
    float acc[B_];
#pragma unroll
    for (int b = 0; b < B_; b++) acc[b] = 0.f;
    int hd0 = hc * 256 + grp * 64;
    for (int i = 0; i < 64; i++) {
        int hd = hd0 + i;
        float w = Wo[(size_t)hd * DM + e];
#pragma unroll
        for (int b = 0; b < B_; b++) acc[b] += of[b * (H_ * DH) + hd] * w;
    }
    if (hc == 0 && grp == 0) {
        float bv = bo[e];
#pragma unroll
        for (int b = 0; b < B_; b++) acc[b] += bv;
    }
#pragma unroll
    for (int b = 0; b < B_; b++) atomicAdd(out + b * DM + e, acc[b]);
}

extern "C" void kernel_launch(void* const* d_in, const int* in_sizes, int n_in,
                              void* d_out, int out_size, void* d_ws, size_t ws_size,
                              hipStream_t stream) {
    const float* x  = (const float*)d_in[0];
    float* ck       = (float*)d_in[1];
    float* cv       = (float*)d_in[2];
    const float* Wq = (const float*)d_in[3];
    const float* bq = (const float*)d_in[4];
    const float* Wk = (const float*)d_in[5];
    const float* bk = (const float*)d_in[6];
    const float* Wv = (const float*)d_in[7];
    const float* bv = (const float*)d_in[8];
    const float* Wo = (const float*)d_in[9];
    const float* bo = (const float*)d_in[10];
    const int* cidx = (const int*)d_in[11];
    float* ws  = (float*)d_ws;
    float* out = (float*)d_out;

    hipMemsetAsync(ws + WS_Q, 0, 3 * (B_ * H_ * DH) * sizeof(float), stream);
    hipMemsetAsync(out, 0, (size_t)out_size * sizeof(float), stream);

    k_table<<<(TMAX * 32) / 256, 256, 0, stream>>>(ws);
    k_qkv<<<dim3(4, H_, 3), 256, 0, stream>>>(x, Wq, Wk, Wv, ws);
    k_scatter<<<B_ * H_, 64, 0, stream>>>(ck, cv, bq, bk, bv, cidx, ws);
    k_attn<<<dim3(SPLIT, H_, B_), 256, 0, stream>>>(ck, cv, cidx, ws);
    k_combine<<<B_ * H_, 64, 0, stream>>>(ws);
    k_oproj<<<dim3(16, 4), 256, 0, stream>>>(Wo, bo, ws, out);
}

// Round 2
// 616.624 us; speedup vs baseline: 1.0826x; 1.0826x over previous
//
#include <hip/hip_runtime.h>
#include <math.h>

typedef float f4 __attribute__((ext_vector_type(4)));

#define B_    16
#define TMAX  4096
#define DM    1024
#define H_    16
#define DH    64
#define SPLIT 8
#define SCALE 0.125f

// ws layout (float offsets)
#define WS_COS   0                 // 131072
#define WS_SIN   131072            // 131072
#define WS_Q     262144            // 16384
#define WS_PO    311296            // B*H*SPLIT*64 = 131072
#define WS_PM    442368            // 2048
#define WS_PL    444416            // 2048
#define WS_OF    446464            // 16384
#define WS_BIG   462848            // max(393216 qkv partials, 262144 oproj partials)
// total 856064 floats = 3.27 MB

__device__ __forceinline__ f4 ldnt(const f4* p) { return __builtin_nontemporal_load(p); }

__device__ __forceinline__ float wred_max(float v) {
#pragma unroll
    for (int o = 32; o > 0; o >>= 1) v = fmaxf(v, __shfl_xor(v, o, 64));
    return v;
}
__device__ __forceinline__ float wred_sum(float v) {
#pragma unroll
    for (int o = 32; o > 0; o >>= 1) v += __shfl_xor(v, o, 64);
    return v;
}

__global__ void k_table(float* __restrict__ ws) {
    int idx = blockIdx.x * 256 + threadIdx.x;   // TMAX*32 threads
    int t = idx >> 5, j = idx & 31;
    float inv = expf(-(float)j * (logf(10000.0f) / 32.0f));
    float ang = (float)t * inv;
    float s, c;
    sincosf(ang, &s, &c);
    ws[WS_COS + idx] = c;
    ws[WS_SIN + idx] = s;
}

// grid (8 echunks, 16 heads, 3 matrices), block 256 = 64 d x 4 e-subgroups
// writes partials to WS_BIG[mat][ec][b][h][d] — no atomics
__global__ __launch_bounds__(256) void k_qkv(const float* __restrict__ x,
                      const float* __restrict__ Wq, const float* __restrict__ Wk,
                      const float* __restrict__ Wv, float* __restrict__ ws) {
    const int ec = blockIdx.x, h = blockIdx.y, mat = blockIdx.z;
    const float* W = (mat == 0) ? Wq : ((mat == 1) ? Wk : Wv);
    const int tid = threadIdx.x;
    const int d = tid & 63, es = tid >> 6;
    __shared__ float xs[B_][128];
    __shared__ float red[4][B_][64];
    for (int i = tid; i < B_ * 128; i += 256) {
        int b = i >> 7, e = i & 127;
        xs[b][e] = x[b * DM + ec * 128 + e];
    }
    __syncthreads();
    float acc[B_];
#pragma unroll
    for (int b = 0; b < B_; b++) acc[b] = 0.f;
    for (int i = 0; i < 32; i++) {
        int el = es * 32 + i;
        int e = ec * 128 + el;
        float w = W[((size_t)e * H_ + h) * DH + d];
#pragma unroll
        for (int b = 0; b < B_; b++) acc[b] += xs[b][el] * w;
    }
#pragma unroll
    for (int b = 0; b < B_; b++) red[es][b][d] = acc[b];
    __syncthreads();
    const int b4 = tid >> 6;
#pragma unroll
    for (int bb = 0; bb < 4; bb++) {
        int b = b4 * 4 + bb;
        float v = red[0][b][d] + red[1][b][d] + red[2][b][d] + red[3][b][d];
        ws[WS_BIG + (((size_t)(mat * 8 + ec) * B_ + b) * H_ + h) * DH + d] = v;
    }
}

// 256 blocks (b*h) x 64 threads: reduce 8 partials, add bias,
// store q to ws, write k/v into cache slot P
__global__ void k_qkvred(float* __restrict__ cached_key, float* __restrict__ cached_value,
                         const float* __restrict__ bq, const float* __restrict__ bk,
                         const float* __restrict__ bv, const int* __restrict__ cidx,
                         float* __restrict__ ws) {
    const int bh = blockIdx.x, d = threadIdx.x;
    const int b = bh >> 4, h = bh & 15;
    const int P = *cidx;
    float q = bq[h * 64 + d], k = bk[h * 64 + d], v = bv[h * 64 + d];
    const float* big = ws + WS_BIG;
    const size_t matstride = (size_t)8 * B_ * H_ * DH;
#pragma unroll
    for (int ec = 0; ec < 8; ec++) {
        size_t base = (((size_t)ec * B_ + b) * H_ + h) * DH + d;
        q += big[base];
        k += big[matstride + base];
        v += big[2 * matstride + base];
    }
    ws[WS_Q + bh * 64 + d] = q;
    size_t off = (((size_t)b * TMAX + P) * H_ + h) * DH + d;
    cached_key[off] = k;
    cached_value[off] = v;
}

// grid (SPLIT, H, B) = 2048 blocks, block 256
__global__ __launch_bounds__(256) void k_attn(const float* __restrict__ K,
                                              const float* __restrict__ V,
                                              const int* __restrict__ cidx,
                                              float* __restrict__ ws) {
    const int s = blockIdx.x, h = blockIdx.y, b = blockIdx.z;
    const int tid = threadIdx.x;
    const int P = *cidx;
    const int n = P + 1;
    const int chunk = (n + SPLIT - 1) / SPLIT;
    const int t0 = s * chunk;
    int t1 = t0 + chunk; if (t1 > n) t1 = n;
    const int len = (t1 > t0) ? (t1 - t0) : 0;
    const int bh = b * H_ + h;
    const float* costab = ws + WS_COS;
    const float* sintab = ws + WS_SIN;

    __shared__ float qr[64];
    __shared__ float sc[512];
    __shared__ float rb_m[4], rb_s[4];
    __shared__ float ov[16][64];

    if (tid < 64) {
        int d = tid;
        const float* q = ws + WS_Q + bh * 64;
        float v;
        if (d < 32) {
            float c = costab[P * 32 + d], sn = sintab[P * 32 + d];
            v = q[d] * c - q[d + 32] * sn;
        } else {
            float c = costab[P * 32 + d - 32], sn = sintab[P * 32 + d - 32];
            v = q[d - 32] * sn + q[d] * c;
        }
        qr[d] = v;
    }
    __syncthreads();

    // Phase A: one thread per position; K via non-temporal float4
    float tmax = -3.0e38f;
    for (int idx = tid; idx < len; idx += 256) {
        int t = t0 + idx;
        const f4* kp = (const f4*)(K + (((size_t)b * TMAX + t) * H_ + h) * DH);
        const f4* cp = (const f4*)(costab + (size_t)t * 32);
        const f4* sp = (const f4*)(sintab + (size_t)t * 32);
        float acc = 0.f;
#pragma unroll
        for (int j4 = 0; j4 < 8; ++j4) {
            f4 c4 = cp[j4], s4 = sp[j4];
            f4 k1 = ldnt(kp + j4), k2 = ldnt(kp + j4 + 8);
            int j = j4 * 4;
            acc += k1.x * (qr[j + 0] * c4.x + qr[j + 32] * s4.x) + k2.x * (qr[j + 32] * c4.x - qr[j + 0] * s4.x);
            acc += k1.y * (qr[j + 1] * c4.y + qr[j + 33] * s4.y) + k2.y * (qr[j + 33] * c4.y - qr[j + 1] * s4.y);
            acc += k1.z * (qr[j + 2] * c4.z + qr[j + 34] * s4.z) + k2.z * (qr[j + 34] * c4.z - qr[j + 2] * s4.z);
            acc += k1.w * (qr[j + 3] * c4.w + qr[j + 35] * s4.w) + k2.w * (qr[j + 35] * c4.w - qr[j + 3] * s4.w);
        }
        float sv = acc * SCALE;
        sc[idx] = sv;
        tmax = fmaxf(tmax, sv);
    }
    float wm = wred_max(tmax);
    if ((tid & 63) == 0) rb_m[tid >> 6] = wm;
    __syncthreads();
    float m = fmaxf(fmaxf(rb_m[0], rb_m[1]), fmaxf(rb_m[2], rb_m[3]));

    float tsum = 0.f;
    for (int idx = tid; idx < len; idx += 256) {
        float p = __expf(sc[idx] - m);
        sc[idx] = p;
        tsum += p;
    }
    float wsum = wred_sum(tsum);
    if ((tid & 63) == 0) rb_s[tid >> 6] = wsum;
    __syncthreads();   // also publishes sc[] p-values for Phase B
    float l = rb_s[0] + rb_s[1] + rb_s[2] + rb_s[3];

    // Phase B: float4 over d, 16 position-groups, non-temporal V
    const int d4 = tid & 15, grp = tid >> 4;
    f4 acc4 = {0.f, 0.f, 0.f, 0.f};
#pragma unroll 4
    for (int idx = grp; idx < len; idx += 16) {
        int t = t0 + idx;
        const f4* vp = (const f4*)(V + (((size_t)b * TMAX + t) * H_ + h) * DH) + d4;
        f4 vv = ldnt(vp);
        acc4 += sc[idx] * vv;
    }
    *(f4*)&ov[grp][d4 * 4] = acc4;
    __syncthreads();
    if (tid < 64) {
        float o = 0.f;
#pragma unroll
        for (int g = 0; g < 16; g++) o += ov[g][tid];
        ws[WS_PO + ((size_t)bh * SPLIT + s) * 64 + tid] = o;
        if (tid == 0) {
            ws[WS_PM + bh * SPLIT + s] = (len > 0) ? m : -1.0e30f;
            ws[WS_PL + bh * SPLIT + s] = l;
        }
    }
}

// 256 blocks x 64 threads
__global__ void k_combine(float* __restrict__ ws) {
    int bh = blockIdx.x;
    int d = threadIdx.x;
    const float* pm = ws + WS_PM + bh * SPLIT;
    const float* pl = ws + WS_PL + bh * SPLIT;
    const float* po = ws + WS_PO + (size_t)bh * SPLIT * 64;
    float m = -3.0e38f;
#pragma unroll
    for (int s = 0; s < SPLIT; s++) m = fmaxf(m, pm[s]);
    float l = 0.f, o = 0.f;
#pragma unroll
    for (int s = 0; s < SPLIT; s++) {
        float w = __expf(pm[s] - m);
        l += pl[s] * w;
        o += po[s * 64 + d] * w;
    }
    ws[WS_OF + bh * 64 + d] = o / l;
}

// grid (16 echunks, 16 hdchunks), block 256 = 64 e x 4 hd-subgroups
// writes partials to WS_BIG[hc][b][e] — no atomics
__global__ __launch_bounds__(256) void k_oproj(const float* __restrict__ Wo,
                        float* __restrict__ ws) {
    const int ec = blockIdx.x, hc = blockIdx.y;
    const int tid = threadIdx.x;
    const int el = tid & 63, grp = tid >> 6;
    const int e = ec * 64 + el;
    __shared__ float ofs[B_][64];
    __shared__ float red[4][B_][64];
    for (int i = tid; i < B_ * 64; i += 256) {
        int b = i >> 6, j = i & 63;
        ofs[b][j] = ws[WS_OF + b * (H_ * DH) + hc * 64 + j];
    }
    __syncthreads();
    float acc[B_];
#pragma unroll
    for (int b = 0; b < B_; b++) acc[b] = 0.f;
    for (int i = 0; i < 16; i++) {
        int hl = grp * 16 + i;
        int hd = hc * 64 + hl;
        float w = Wo[(size_t)hd * DM + e];
#pragma unroll
        for (int b = 0; b < B_; b++) acc[b] += ofs[b][hl] * w;
    }
#pragma unroll
    for (int b = 0; b < B_; b++) red[grp][b][el] = acc[b];
    __syncthreads();
    const int b4 = tid >> 6;
#pragma unroll
    for (int bb = 0; bb < 4; bb++) {
        int b = b4 * 4 + bb;
        float v = red[0][b][el] + red[1][b][el] + red[2][b][el] + red[3][b][el];
        ws[WS_BIG + ((size_t)hc * B_ + b) * DM + ec * 64 + el] = v;
    }
}

// 64 blocks x 256 threads: out = sum of 16 hc partials + bias
__global__ void k_out(const float* __restrict__ bo, const float* __restrict__ ws,
                      float* __restrict__ out) {
    int idx = blockIdx.x * 256 + threadIdx.x;   // b*1024+e
    int e = idx & (DM - 1);
    float v = bo[e];
#pragma unroll
    for (int hc = 0; hc < 16; hc++) v += ws[WS_BIG + (size_t)hc * B_ * DM + idx];
    out[idx] = v;
}

extern "C" void kernel_launch(void* const* d_in, const int* in_sizes, int n_in,
                              void* d_out, int out_size, void* d_ws, size_t ws_size,
                              hipStream_t stream) {
    const float* x  = (const float*)d_in[0];
    float* ck       = (float*)d_in[1];
    float* cv       = (float*)d_in[2];
    const float* Wq = (const float*)d_in[3];
    const float* bq = (const float*)d_in[4];
    const float* Wk = (const float*)d_in[5];
    const float* bk = (const float*)d_in[6];
    const float* Wv = (const float*)d_in[7];
    const float* bv = (const float*)d_in[8];
    const float* Wo = (const float*)d_in[9];
    const float* bo = (const float*)d_in[10];
    const int* cidx = (const int*)d_in[11];
    float* ws  = (float*)d_ws;
    float* out = (float*)d_out;

    k_table<<<(TMAX * 32) / 256, 256, 0, stream>>>(ws);
    k_qkv<<<dim3(8, H_, 3), 256, 0, stream>>>(x, Wq, Wk, Wv, ws);
    k_qkvred<<<B_ * H_, 64, 0, stream>>>(ck, cv, bq, bk, bv, cidx, ws);
    k_attn<<<dim3(SPLIT, H_, B_), 256, 0, stream>>>(ck, cv, cidx, ws);
    k_combine<<<B_ * H_, 64, 0, stream>>>(ws);
    k_oproj<<<dim3(16, 16), 256, 0, stream>>>(Wo, ws);
    k_out<<<64, 256, 0, stream>>>(bo, ws, out);
}

// Round 3
// 483.097 us; speedup vs baseline: 1.3818x; 1.2764x over previous
//
#include <hip/hip_runtime.h>
#include <math.h>

typedef float f4 __attribute__((ext_vector_type(4)));

#define B_    16
#define TMAX  4096
#define DM    1024
#define H_    16
#define DH    64
#define SPLIT 8
#define SCALE 0.125f
#define ROPE_L 0.28782313662425572f   // ln(10000)/32

// ws layout (float offsets)
#define WS_Q     0                 // 16384
#define WS_PO    16384             // B*H*SPLIT*64 = 131072
#define WS_PM    147456            // 2048
#define WS_PL    149504            // 2048
#define WS_OF    151552            // 16384
#define WS_BIG   167936            // max(393216 qkv partials, 262144 oproj partials)

__device__ __forceinline__ f4 ldnt(const f4* p) { return __builtin_nontemporal_load(p); }

__device__ __forceinline__ float wred_max(float v) {
#pragma unroll
    for (int o = 32; o > 0; o >>= 1) v = fmaxf(v, __shfl_xor(v, o, 64));
    return v;
}
__device__ __forceinline__ float wred_sum(float v) {
#pragma unroll
    for (int o = 32; o > 0; o >>= 1) v += __shfl_xor(v, o, 64);
    return v;
}

// grid (8 echunks, 16 heads, 3 matrices), block 256 = 64 d x 4 e-subgroups
__global__ __launch_bounds__(256) void k_qkv(const float* __restrict__ x,
                      const float* __restrict__ Wq, const float* __restrict__ Wk,
                      const float* __restrict__ Wv, float* __restrict__ ws) {
    const int ec = blockIdx.x, h = blockIdx.y, mat = blockIdx.z;
    const float* W = (mat == 0) ? Wq : ((mat == 1) ? Wk : Wv);
    const int tid = threadIdx.x;
    const int d = tid & 63, es = tid >> 6;
    __shared__ float xs[B_][128];
    __shared__ float red[4][B_][64];
    for (int i = tid; i < B_ * 128; i += 256) {
        int b = i >> 7, e = i & 127;
        xs[b][e] = x[b * DM + ec * 128 + e];
    }
    __syncthreads();
    float acc[B_];
#pragma unroll
    for (int b = 0; b < B_; b++) acc[b] = 0.f;
    for (int i = 0; i < 32; i++) {
        int el = es * 32 + i;
        int e = ec * 128 + el;
        float w = W[((size_t)e * H_ + h) * DH + d];
#pragma unroll
        for (int b = 0; b < B_; b++) acc[b] += xs[b][el] * w;
    }
#pragma unroll
    for (int b = 0; b < B_; b++) red[es][b][d] = acc[b];
    __syncthreads();
    const int b4 = tid >> 6;
#pragma unroll
    for (int bb = 0; bb < 4; bb++) {
        int b = b4 * 4 + bb;
        float v = red[0][b][d] + red[1][b][d] + red[2][b][d] + red[3][b][d];
        ws[WS_BIG + (((size_t)(mat * 8 + ec) * B_ + b) * H_ + h) * DH + d] = v;
    }
}

// 256 blocks (b*h) x 64 threads
__global__ void k_qkvred(float* __restrict__ cached_key, float* __restrict__ cached_value,
                         const float* __restrict__ bq, const float* __restrict__ bk,
                         const float* __restrict__ bv, const int* __restrict__ cidx,
                         float* __restrict__ ws) {
    const int bh = blockIdx.x, d = threadIdx.x;
    const int b = bh >> 4, h = bh & 15;
    const int P = *cidx;
    float q = bq[h * 64 + d], k = bk[h * 64 + d], v = bv[h * 64 + d];
    const float* big = ws + WS_BIG;
    const size_t matstride = (size_t)8 * B_ * H_ * DH;
#pragma unroll
    for (int ec = 0; ec < 8; ec++) {
        size_t base = (((size_t)ec * B_ + b) * H_ + h) * DH + d;
        q += big[base];
        k += big[matstride + base];
        v += big[2 * matstride + base];
    }
    ws[WS_Q + bh * 64 + d] = q;
    size_t off = (((size_t)b * TMAX + P) * H_ + h) * DH + d;
    cached_key[off] = k;
    cached_value[off] = v;
}

// grid (SPLIT, H, B) = 2048 blocks, block 256
__global__ __launch_bounds__(256) void k_attn(const float* __restrict__ K,
                                              const float* __restrict__ V,
                                              const int* __restrict__ cidx,
                                              float* __restrict__ ws) {
    const int s = blockIdx.x, h = blockIdx.y, b = blockIdx.z;
    const int tid = threadIdx.x;
    const int P = *cidx;
    const int n = P + 1;
    const int chunk = (n + SPLIT - 1) / SPLIT;
    const int t0 = s * chunk;
    int t1 = t0 + chunk; if (t1 > n) t1 = n;
    const int len = (t1 > t0) ? (t1 - t0) : 0;
    const int bh = b * H_ + h;

    __shared__ float qr[64];
    __shared__ float sc[512];
    __shared__ float rb_m[4], rb_s[4];
    __shared__ float ov[16][64];

    if (tid < 64) {
        int d = tid;
        const float* qv = ws + WS_Q + bh * 64;
        int j = (d < 32) ? d : (d - 32);
        float invf = __expf(-(float)j * ROPE_L);
        float sn, c;
        sincosf((float)P * invf, &sn, &c);
        qr[d] = (d < 32) ? (qv[d] * c - qv[d + 32] * sn)
                         : (qv[d - 32] * sn + qv[d] * c);
    }
    __syncthreads();

    // Phase A: 8 lanes per position, fully-coalesced K rows
    const int pos_sub = tid >> 3, q = tid & 7;
    float qa0 = qr[4 * q + 0], qa1 = qr[4 * q + 1], qa2 = qr[4 * q + 2], qa3 = qr[4 * q + 3];
    float qb0 = qr[4 * q + 32], qb1 = qr[4 * q + 33], qb2 = qr[4 * q + 34], qb3 = qr[4 * q + 35];
    float if0 = __expf(-(float)(4 * q + 0) * ROPE_L);
    float if1 = __expf(-(float)(4 * q + 1) * ROPE_L);
    float if2 = __expf(-(float)(4 * q + 2) * ROPE_L);
    float if3 = __expf(-(float)(4 * q + 3) * ROPE_L);

    float tmax = -3.0e38f;
    for (int base = 0; base < len; base += 32) {
        int idx = base + pos_sub;
        bool act = idx < len;
        int t = t0 + idx;
        f4 k1 = {0.f, 0.f, 0.f, 0.f}, k2 = {0.f, 0.f, 0.f, 0.f};
        if (act) {
            const f4* kp = (const f4*)(K + (((size_t)b * TMAX + t) * H_ + h) * DH);
            k1 = ldnt(kp + q);
            k2 = ldnt(kp + q + 8);
        }
        float tf = (float)t;
        float s0, c0, s1, c1, s2, c2, s3, c3;
        sincosf(tf * if0, &s0, &c0);
        sincosf(tf * if1, &s1, &c1);
        sincosf(tf * if2, &s2, &c2);
        sincosf(tf * if3, &s3, &c3);
        float p = k1.x * (qa0 * c0 + qb0 * s0) + k2.x * (qb0 * c0 - qa0 * s0)
                + k1.y * (qa1 * c1 + qb1 * s1) + k2.y * (qb1 * c1 - qa1 * s1)
                + k1.z * (qa2 * c2 + qb2 * s2) + k2.z * (qb2 * c2 - qa2 * s2)
                + k1.w * (qa3 * c3 + qb3 * s3) + k2.w * (qb3 * c3 - qa3 * s3);
#pragma unroll
        for (int o = 1; o < 8; o <<= 1) p += __shfl_xor(p, o, 64);
        if (act) {
            float sv = p * SCALE;
            if (q == 0) sc[idx] = sv;
            tmax = fmaxf(tmax, sv);
        }
    }
    float wm = wred_max(tmax);
    if ((tid & 63) == 0) rb_m[tid >> 6] = wm;
    __syncthreads();
    float m = fmaxf(fmaxf(rb_m[0], rb_m[1]), fmaxf(rb_m[2], rb_m[3]));

    float tsum = 0.f;
    for (int idx = tid; idx < len; idx += 256) {
        float pp = __expf(sc[idx] - m);
        sc[idx] = pp;
        tsum += pp;
    }
    float wsum = wred_sum(tsum);
    if ((tid & 63) == 0) rb_s[tid >> 6] = wsum;
    __syncthreads();
    float l = rb_s[0] + rb_s[1] + rb_s[2] + rb_s[3];

    // Phase B: float4 over d, 16 position-groups, coalesced rows
    const int d4 = tid & 15, grp = tid >> 4;
    f4 acc4 = {0.f, 0.f, 0.f, 0.f};
#pragma unroll 4
    for (int idx = grp; idx < len; idx += 16) {
        int t = t0 + idx;
        const f4* vp = (const f4*)(V + (((size_t)b * TMAX + t) * H_ + h) * DH) + d4;
        f4 vv = ldnt(vp);
        acc4 += sc[idx] * vv;
    }
    *(f4*)&ov[grp][d4 * 4] = acc4;
    __syncthreads();
    if (tid < 64) {
        float o = 0.f;
#pragma unroll
        for (int g = 0; g < 16; g++) o += ov[g][tid];
        ws[WS_PO + ((size_t)bh * SPLIT + s) * 64 + tid] = o;
        if (tid == 0) {
            ws[WS_PM + bh * SPLIT + s] = (len > 0) ? m : -1.0e30f;
            ws[WS_PL + bh * SPLIT + s] = l;
        }
    }
}

// 256 blocks x 64 threads
__global__ void k_combine(float* __restrict__ ws) {
    int bh = blockIdx.x;
    int d = threadIdx.x;
    const float* pm = ws + WS_PM + bh * SPLIT;
    const float* pl = ws + WS_PL + bh * SPLIT;
    const float* po = ws + WS_PO + (size_t)bh * SPLIT * 64;
    float m = -3.0e38f;
#pragma unroll
    for (int s = 0; s < SPLIT; s++) m = fmaxf(m, pm[s]);
    float l = 0.f, o = 0.f;
#pragma unroll
    for (int s = 0; s < SPLIT; s++) {
        float w = __expf(pm[s] - m);
        l += pl[s] * w;
        o += po[s * 64 + d] * w;
    }
    ws[WS_OF + bh * 64 + d] = o / l;
}

// grid (16 echunks, 16 hdchunks), block 256
__global__ __launch_bounds__(256) void k_oproj(const float* __restrict__ Wo,
                        float* __restrict__ ws) {
    const int ec = blockIdx.x, hc = blockIdx.y;
    const int tid = threadIdx.x;
    const int el = tid & 63, grp = tid >> 6;
    const int e = ec * 64 + el;
    __shared__ float ofs[B_][64];
    __shared__ float red[4][B_][64];
    for (int i = tid; i < B_ * 64; i += 256) {
        int b = i >> 6, j = i & 63;
        ofs[b][j] = ws[WS_OF + b * (H_ * DH) + hc * 64 + j];
    }
    __syncthreads();
    float acc[B_];
#pragma unroll
    for (int b = 0; b < B_; b++) acc[b] = 0.f;
    for (int i = 0; i < 16; i++) {
        int hl = grp * 16 + i;
        int hd = hc * 64 + hl;
        float w = Wo[(size_t)hd * DM + e];
#pragma unroll
        for (int b = 0; b < B_; b++) acc[b] += ofs[b][hl] * w;
    }
#pragma unroll
    for (int b = 0; b < B_; b++) red[grp][b][el] = acc[b];
    __syncthreads();
    const int b4 = tid >> 6;
#pragma unroll
    for (int bb = 0; bb < 4; bb++) {
        int b = b4 * 4 + bb;
        float v = red[0][b][el] + red[1][b][el] + red[2][b][el] + red[3][b][el];
        ws[WS_BIG + ((size_t)hc * B_ + b) * DM + ec * 64 + el] = v;
    }
}

// 64 blocks x 256 threads
__global__ void k_out(const float* __restrict__ bo, const float* __restrict__ ws,
                      float* __restrict__ out) {
    int idx = blockIdx.x * 256 + threadIdx.x;
    int e = idx & (DM - 1);
    float v = bo[e];
#pragma unroll
    for (int hc = 0; hc < 16; hc++) v += ws[WS_BIG + (size_t)hc * B_ * DM + idx];
    out[idx] = v;
}

extern "C" void kernel_launch(void* const* d_in, const int* in_sizes, int n_in,
                              void* d_out, int out_size, void* d_ws, size_t ws_size,
                              hipStream_t stream) {
    const float* x  = (const float*)d_in[0];
    float* ck       = (float*)d_in[1];
    float* cv       = (float*)d_in[2];
    const float* Wq = (const float*)d_in[3];
    const float* bq = (const float*)d_in[4];
    const float* Wk = (const float*)d_in[5];
    const float* bk = (const float*)d_in[6];
    const float* Wv = (const float*)d_in[7];
    const float* bv = (const float*)d_in[8];
    const float* Wo = (const float*)d_in[9];
    const float* bo = (const float*)d_in[10];
    const int* cidx = (const int*)d_in[11];
    float* ws  = (float*)d_ws;
    float* out = (float*)d_out;

    k_qkv<<<dim3(8, H_, 3), 256, 0, stream>>>(x, Wq, Wk, Wv, ws);
    k_qkvred<<<B_ * H_, 64, 0, stream>>>(ck, cv, bq, bk, bv, cidx, ws);
    k_attn<<<dim3(SPLIT, H_, B_), 256, 0, stream>>>(ck, cv, cidx, ws);
    k_combine<<<B_ * H_, 64, 0, stream>>>(ws);
    k_oproj<<<dim3(16, 16), 256, 0, stream>>>(Wo, ws);
    k_out<<<64, 256, 0, stream>>>(bo, ws, out);
}